// Round 1
// baseline (1220.652 us; speedup 1.0000x reference)
//
#include <hip/hip_runtime.h>
#include <hip/hip_bf16.h>

// GCN layer: out = relu( (D^-1/2 A D^-1/2) (x @ w) + b )
// Strategy:
//   1. hist:    deg[r] += val, cnt[r] += 1           (atomics, small)
//   2. dinv:    dinv = deg>0 ? 1/sqrt(deg) : 0
//   3. scan:    row_start = exclusive_scan(cnt)       (single 1024-thread block)
//   4. scatter: CSR build — sorted (col, norm_val) per row (atomic fill counters)
//   5. gemm:    h = x @ w, fp32 vector SGEMM, stored as bf16 (halves gather traffic;
//               error ~2e-3 << 2.9e-2 threshold)
//   6. agg:     one wave per node, lane l owns features 4l..4l+3; stream the node's
//               CSR edges, gather bf16 h rows (coalesced 512B/edge), fp32 accumulate,
//               fused bias + relu. No atomics in the hot phase.

#define DF 256   // D_FEAT == FILTERS == 256

__device__ __forceinline__ unsigned short f2bf(float f) {
    unsigned int u = __float_as_uint(f);
    unsigned int r = (u + 0x7fffu + ((u >> 16) & 1u)) >> 16;  // RNE
    return (unsigned short)r;
}
__device__ __forceinline__ float bflo(unsigned int u) { return __uint_as_float(u << 16); }
__device__ __forceinline__ float bfhi(unsigned int u) { return __uint_as_float(u & 0xffff0000u); }

__global__ void hist_kernel(const int* __restrict__ row, const float* __restrict__ vals,
                            float* __restrict__ deg, int* __restrict__ cnt, int E) {
    int e = blockIdx.x * blockDim.x + threadIdx.x;
    if (e < E) {
        int r = row[e];
        atomicAdd(&deg[r], vals[e]);
        atomicAdd(&cnt[r], 1);
    }
}

__global__ void dinv_kernel(const float* __restrict__ deg, float* __restrict__ dinv, int N) {
    int i = blockIdx.x * blockDim.x + threadIdx.x;
    if (i < N) {
        float d = deg[i];
        dinv[i] = (d > 0.f) ? (1.0f / sqrtf(d)) : 0.f;
    }
}

__global__ __launch_bounds__(1024) void scan_kernel(const int* __restrict__ cnt,
                                                    int* __restrict__ row_start, int N) {
    const int T = 1024;
    int tid = threadIdx.x;
    int chunk = (N + T - 1) / T;
    int begin = tid * chunk;
    int end = begin + chunk; if (end > N) end = N;
    int sum = 0;
    for (int i = begin; i < end; ++i) sum += cnt[i];
    __shared__ int ps[T];
    ps[tid] = sum;
    __syncthreads();
    // Hillis-Steele inclusive scan
    for (int off = 1; off < T; off <<= 1) {
        int v = (tid >= off) ? ps[tid - off] : 0;
        __syncthreads();
        ps[tid] += v;
        __syncthreads();
    }
    int run = (tid == 0) ? 0 : ps[tid - 1];
    for (int i = begin; i < end; ++i) { row_start[i] = run; run += cnt[i]; }
    if (tid == T - 1) row_start[N] = ps[T - 1];
}

__global__ void scatter_kernel(const int* __restrict__ row, const int* __restrict__ col,
                               const float* __restrict__ vals, const float* __restrict__ dinv,
                               const int* __restrict__ row_start, int* __restrict__ fill,
                               int* __restrict__ scol, float* __restrict__ sval, int E) {
    int e = blockIdx.x * blockDim.x + threadIdx.x;
    if (e < E) {
        int r = row[e], c = col[e];
        int p = row_start[r] + atomicAdd(&fill[r], 1);
        scol[p] = c;
        sval[p] = vals[e] * dinv[r] * dinv[c];
    }
}

// fp32 SGEMM: C[N x 256] = x[N x 256] @ w[256 x 256], store bf16.
// 128x128 tile, BK=8, 256 threads, 8x8 micro-tile per thread.
#define BM 128
#define BN 128
#define BK 8
__global__ __launch_bounds__(256) void gemm_kernel(const float* __restrict__ x,
                                                   const float* __restrict__ w,
                                                   unsigned short* __restrict__ h, int N) {
    __shared__ float As[BK][BM];
    __shared__ float Bs[BK][BN];
    int tid = threadIdx.x;
    int by = blockIdx.x;       // row block
    int bx = blockIdx.y;       // col block (0..1)
    int tx = tid & 15, ty = tid >> 4;

    float acc[8][8];
#pragma unroll
    for (int i = 0; i < 8; ++i)
#pragma unroll
        for (int j = 0; j < 8; ++j) acc[i][j] = 0.f;

    int arow = tid >> 1;             // 0..127
    int ah   = (tid & 1) * 4;        // 0 or 4
    int grow = by * BM + arow; if (grow >= N) grow = N - 1;   // clamp (stores guarded)
    const float* aptr = x + (long)grow * DF + ah;
    int bk = tid >> 5;               // 0..7
    int bc = (tid & 31) * 4;
    const float* bptr = w + bk * DF + bx * BN + bc;

    for (int kk = 0; kk < DF; kk += BK) {
        float4 a4 = *(const float4*)(aptr + kk);
        float4 b4 = *(const float4*)(bptr + (long)kk * DF);
        As[ah + 0][arow] = a4.x;
        As[ah + 1][arow] = a4.y;
        As[ah + 2][arow] = a4.z;
        As[ah + 3][arow] = a4.w;
        *(float4*)&Bs[bk][bc] = b4;
        __syncthreads();
#pragma unroll
        for (int k = 0; k < BK; ++k) {
            float a[8], b[8];
            *(float4*)&a[0] = *(const float4*)&As[k][ty * 8];
            *(float4*)&a[4] = *(const float4*)&As[k][ty * 8 + 4];
            *(float4*)&b[0] = *(const float4*)&Bs[k][tx * 8];
            *(float4*)&b[4] = *(const float4*)&Bs[k][tx * 8 + 4];
#pragma unroll
            for (int i = 0; i < 8; ++i)
#pragma unroll
                for (int j = 0; j < 8; ++j)
                    acc[i][j] += a[i] * b[j];
        }
        __syncthreads();
    }

#pragma unroll
    for (int i = 0; i < 8; ++i) {
        int r = by * BM + ty * 8 + i;
        if (r < N) {
            uint4 o;
            o.x = (unsigned)f2bf(acc[i][0]) | ((unsigned)f2bf(acc[i][1]) << 16);
            o.y = (unsigned)f2bf(acc[i][2]) | ((unsigned)f2bf(acc[i][3]) << 16);
            o.z = (unsigned)f2bf(acc[i][4]) | ((unsigned)f2bf(acc[i][5]) << 16);
            o.w = (unsigned)f2bf(acc[i][6]) | ((unsigned)f2bf(acc[i][7]) << 16);
            *(uint4*)(h + (long)r * DF + bx * BN + tx * 8) = o;
        }
    }
}

// One wave per node. lane l owns features [4l, 4l+4). 2-edge unrolled gather.
__global__ __launch_bounds__(256) void agg_kernel(const unsigned short* __restrict__ h,
                                                  const int* __restrict__ row_start,
                                                  const int* __restrict__ scol,
                                                  const float* __restrict__ sval,
                                                  const float* __restrict__ bias,
                                                  float* __restrict__ out, int N) {
    int wave = threadIdx.x >> 6;
    int lane = threadIdx.x & 63;
    int r = blockIdx.x * 4 + wave;
    if (r >= N) return;
    int s = row_start[r], e = row_start[r + 1];
    float4 acc = {0.f, 0.f, 0.f, 0.f};
    const unsigned short* hp = h + lane * 4;
    int i = s;
    for (; i + 1 < e; i += 2) {
        int c0 = scol[i], c1 = scol[i + 1];
        float v0 = sval[i], v1 = sval[i + 1];
        uint2 u0 = *(const uint2*)(hp + (long)c0 * DF);
        uint2 u1 = *(const uint2*)(hp + (long)c1 * DF);
        acc.x += v0 * bflo(u0.x) + v1 * bflo(u1.x);
        acc.y += v0 * bfhi(u0.x) + v1 * bfhi(u1.x);
        acc.z += v0 * bflo(u0.y) + v1 * bflo(u1.y);
        acc.w += v0 * bfhi(u0.y) + v1 * bfhi(u1.y);
    }
    if (i < e) {
        int c0 = scol[i];
        float v0 = sval[i];
        uint2 u0 = *(const uint2*)(hp + (long)c0 * DF);
        acc.x += v0 * bflo(u0.x);
        acc.y += v0 * bfhi(u0.x);
        acc.z += v0 * bflo(u0.y);
        acc.w += v0 * bfhi(u0.y);
    }
    float4 bb = *(const float4*)(bias + lane * 4);
    float4 o;
    o.x = fmaxf(acc.x + bb.x, 0.f);
    o.y = fmaxf(acc.y + bb.y, 0.f);
    o.z = fmaxf(acc.z + bb.z, 0.f);
    o.w = fmaxf(acc.w + bb.w, 0.f);
    *(float4*)(out + (long)r * DF + lane * 4) = o;
}

extern "C" void kernel_launch(void* const* d_in, const int* in_sizes, int n_in,
                              void* d_out, int out_size, void* d_ws, size_t ws_size,
                              hipStream_t stream) {
    const float* x   = (const float*)d_in[0];
    const int* erow  = (const int*)d_in[1];
    const int* ecol  = (const int*)d_in[2];
    const float* ev  = (const float*)d_in[3];
    const float* w   = (const float*)d_in[4];
    const float* b   = (const float*)d_in[5];
    float* out = (float*)d_out;

    int N = in_sizes[0] / DF;
    int E = in_sizes[1];

    char* ws = (char*)d_ws;
    size_t Na  = (((size_t)N * 4) + 255) & ~(size_t)255;        // aligned N*4
    size_t RSa = (((size_t)(N + 1) * 4) + 255) & ~(size_t)255;  // aligned (N+1)*4
    size_t Ea  = (((size_t)E * 4) + 255) & ~(size_t)255;        // aligned E*4

    float* deg      = (float*)(ws + 0 * Na);
    int*   cnt      = (int*)  (ws + 1 * Na);
    int*   fill     = (int*)  (ws + 2 * Na);
    float* dinv     = (float*)(ws + 3 * Na);
    int*   rstart   = (int*)  (ws + 4 * Na);
    int*   scol     = (int*)  (ws + 4 * Na + RSa);
    float* sval     = (float*)(ws + 4 * Na + RSa + Ea);
    unsigned short* h = (unsigned short*)(ws + 4 * Na + RSa + 2 * Ea);
    // total ws use: 4*Na + RSa + 2*Ea + N*DF*2  (~78.6 MB for this problem)

    hipMemsetAsync(d_ws, 0, 3 * Na, stream);  // zero deg, cnt, fill

    hist_kernel<<<(E + 255) / 256, 256, 0, stream>>>(erow, ev, deg, cnt, E);
    dinv_kernel<<<(N + 255) / 256, 256, 0, stream>>>(deg, dinv, N);
    scan_kernel<<<1, 1024, 0, stream>>>(cnt, rstart, N);
    scatter_kernel<<<(E + 255) / 256, 256, 0, stream>>>(erow, ecol, ev, dinv, rstart, fill,
                                                        scol, sval, E);
    gemm_kernel<<<dim3((N + BM - 1) / BM, DF / BN), 256, 0, stream>>>(x, w, h, N);
    agg_kernel<<<(N + 3) / 4, 256, 0, stream>>>(h, rstart, scol, sval, b, out, N);
}

// Round 2
// 944.736 us; speedup vs baseline: 1.2921x; 1.2921x over previous
//
#include <hip/hip_runtime.h>
#include <hip/hip_bf16.h>

// GCN layer: out = relu( (D^-1/2 A D^-1/2) (x @ w) + b )
//
// R2: device-scope atomics on gfx950 execute as HBM-side 32B RMWs (R1 rocprof:
// hist WRITE_SIZE 199MB = 6.4M atomics x 32B, 277us). So: one atomic per edge
// total. hist_rank captures atomicAdd's return as the edge's intra-row rank,
// making scatter atomic-free. deg is computed post-CSR by contiguous segment
// sum (no float atomics). dinv folded algebraically:
//   out[r] = relu( dinv[r] * sum_e val_e * (dinv[c_e] * h[c_e]) + b )
// with h' = dinv[c]*h[c] applied in the GEMM epilogue (free).

#define DF 256   // D_FEAT == FILTERS == 256

__device__ __forceinline__ unsigned short f2bf(float f) {
    unsigned int u = __float_as_uint(f);
    unsigned int r = (u + 0x7fffu + ((u >> 16) & 1u)) >> 16;  // RNE
    return (unsigned short)r;
}
__device__ __forceinline__ float bflo(unsigned int u) { return __uint_as_float(u << 16); }
__device__ __forceinline__ float bfhi(unsigned int u) { return __uint_as_float(u & 0xffff0000u); }

// rank[e] = position of edge e within its row; cnt[r] = degree count
__global__ void hist_rank_kernel(const int* __restrict__ row, int* __restrict__ cnt,
                                 int* __restrict__ rank, int E) {
    int e = blockIdx.x * blockDim.x + threadIdx.x;
    if (e < E) rank[e] = atomicAdd(&cnt[row[e]], 1);
}

__global__ __launch_bounds__(1024) void scan_kernel(const int* __restrict__ cnt,
                                                    int* __restrict__ row_start, int N) {
    const int T = 1024;
    int tid = threadIdx.x;
    int chunk = (N + T - 1) / T;
    int begin = tid * chunk;
    int end = begin + chunk; if (end > N) end = N;
    int sum = 0;
    for (int i = begin; i < end; ++i) sum += cnt[i];
    __shared__ int ps[T];
    ps[tid] = sum;
    __syncthreads();
    for (int off = 1; off < T; off <<= 1) {
        int v = (tid >= off) ? ps[tid - off] : 0;
        __syncthreads();
        ps[tid] += v;
        __syncthreads();
    }
    int run = (tid == 0) ? 0 : ps[tid - 1];
    for (int i = begin; i < end; ++i) { row_start[i] = run; run += cnt[i]; }
    if (tid == T - 1) row_start[N] = ps[T - 1];
}

// Atomic-free scatter: p = row_start[row] + rank. Packs (col, val) into int2
// so each edge is one 8B scattered write (one 32B sector, not two).
__global__ void scatter_kernel(const int* __restrict__ row, const int* __restrict__ col,
                               const float* __restrict__ vals, const int* __restrict__ row_start,
                               const int* __restrict__ rank, int2* __restrict__ scv, int E) {
    int e = blockIdx.x * blockDim.x + threadIdx.x;
    if (e < E) {
        int r = row[e];
        int p = row_start[r] + rank[e];
        scv[p] = make_int2(col[e], __float_as_int(vals[e]));
    }
}

// deg[r] = sum of vals over the (contiguous) CSR segment; dinv fused.
__global__ void degsum_kernel(const int2* __restrict__ scv, const int* __restrict__ row_start,
                              float* __restrict__ dinv, int N) {
    int r = blockIdx.x * blockDim.x + threadIdx.x;
    if (r < N) {
        int s = row_start[r], e = row_start[r + 1];
        float d = 0.f;
        for (int i = s; i < e; ++i) d += __int_as_float(scv[i].y);
        dinv[r] = (d > 0.f) ? (1.0f / sqrtf(d)) : 0.f;
    }
}

// fp32 SGEMM: h'[r,:] = dinv[r] * (x[r,:] @ w), stored bf16.
// 128x128 tile, BK=8, 256 threads, 8x8 micro-tile per thread.
#define BM 128
#define BN 128
#define BK 8
__global__ __launch_bounds__(256) void gemm_kernel(const float* __restrict__ x,
                                                   const float* __restrict__ w,
                                                   const float* __restrict__ dinv,
                                                   unsigned short* __restrict__ h, int N) {
    __shared__ float As[BK][BM];
    __shared__ float Bs[BK][BN];
    int tid = threadIdx.x;
    int by = blockIdx.x;       // row block
    int bx = blockIdx.y;       // col block (0..1)
    int tx = tid & 15, ty = tid >> 4;

    float acc[8][8];
#pragma unroll
    for (int i = 0; i < 8; ++i)
#pragma unroll
        for (int j = 0; j < 8; ++j) acc[i][j] = 0.f;

    int arow = tid >> 1;             // 0..127
    int ah   = (tid & 1) * 4;        // 0 or 4
    int grow = by * BM + arow; if (grow >= N) grow = N - 1;   // clamp (stores guarded)
    const float* aptr = x + (long)grow * DF + ah;
    int bk = tid >> 5;               // 0..7
    int bc = (tid & 31) * 4;
    const float* bptr = w + bk * DF + bx * BN + bc;

    for (int kk = 0; kk < DF; kk += BK) {
        float4 a4 = *(const float4*)(aptr + kk);
        float4 b4 = *(const float4*)(bptr + (long)kk * DF);
        As[ah + 0][arow] = a4.x;
        As[ah + 1][arow] = a4.y;
        As[ah + 2][arow] = a4.z;
        As[ah + 3][arow] = a4.w;
        *(float4*)&Bs[bk][bc] = b4;
        __syncthreads();
#pragma unroll
        for (int k = 0; k < BK; ++k) {
            float a[8], b[8];
            *(float4*)&a[0] = *(const float4*)&As[k][ty * 8];
            *(float4*)&a[4] = *(const float4*)&As[k][ty * 8 + 4];
            *(float4*)&b[0] = *(const float4*)&Bs[k][tx * 8];
            *(float4*)&b[4] = *(const float4*)&Bs[k][tx * 8 + 4];
#pragma unroll
            for (int i = 0; i < 8; ++i)
#pragma unroll
                for (int j = 0; j < 8; ++j)
                    acc[i][j] += a[i] * b[j];
        }
        __syncthreads();
    }

#pragma unroll
    for (int i = 0; i < 8; ++i) {
        int r = by * BM + ty * 8 + i;
        if (r < N) {
            float dr = dinv[r];
            uint4 o;
            o.x = (unsigned)f2bf(dr * acc[i][0]) | ((unsigned)f2bf(dr * acc[i][1]) << 16);
            o.y = (unsigned)f2bf(dr * acc[i][2]) | ((unsigned)f2bf(dr * acc[i][3]) << 16);
            o.z = (unsigned)f2bf(dr * acc[i][4]) | ((unsigned)f2bf(dr * acc[i][5]) << 16);
            o.w = (unsigned)f2bf(dr * acc[i][6]) | ((unsigned)f2bf(dr * acc[i][7]) << 16);
            *(uint4*)(h + (long)r * DF + bx * BN + tx * 8) = o;
        }
    }
}

// One wave per node, lane l owns features [4l, 4l+4). 4-edge unrolled gather
// for memory-level parallelism. out = relu(dinv[r] * acc + b).
__global__ __launch_bounds__(256) void agg_kernel(const unsigned short* __restrict__ h,
                                                  const int* __restrict__ row_start,
                                                  const int2* __restrict__ scv,
                                                  const float* __restrict__ dinv,
                                                  const float* __restrict__ bias,
                                                  float* __restrict__ out, int N) {
    int wave = threadIdx.x >> 6;
    int lane = threadIdx.x & 63;
    int r = blockIdx.x * 4 + wave;
    if (r >= N) return;
    int s = row_start[r], e = row_start[r + 1];
    float4 acc = {0.f, 0.f, 0.f, 0.f};
    const unsigned short* hp = h + lane * 4;
    int i = s;
    for (; i + 3 < e; i += 4) {
        int2 e0 = scv[i], e1 = scv[i + 1], e2 = scv[i + 2], e3 = scv[i + 3];
        uint2 u0 = *(const uint2*)(hp + (long)e0.x * DF);
        uint2 u1 = *(const uint2*)(hp + (long)e1.x * DF);
        uint2 u2 = *(const uint2*)(hp + (long)e2.x * DF);
        uint2 u3 = *(const uint2*)(hp + (long)e3.x * DF);
        float v0 = __int_as_float(e0.y), v1 = __int_as_float(e1.y);
        float v2 = __int_as_float(e2.y), v3 = __int_as_float(e3.y);
        acc.x += v0 * bflo(u0.x) + v1 * bflo(u1.x) + v2 * bflo(u2.x) + v3 * bflo(u3.x);
        acc.y += v0 * bfhi(u0.x) + v1 * bfhi(u1.x) + v2 * bfhi(u2.x) + v3 * bfhi(u3.x);
        acc.z += v0 * bflo(u0.y) + v1 * bflo(u1.y) + v2 * bflo(u2.y) + v3 * bflo(u3.y);
        acc.w += v0 * bfhi(u0.y) + v1 * bfhi(u1.y) + v2 * bfhi(u2.y) + v3 * bfhi(u3.y);
    }
    for (; i < e; ++i) {
        int2 e0 = scv[i];
        float v0 = __int_as_float(e0.y);
        uint2 u0 = *(const uint2*)(hp + (long)e0.x * DF);
        acc.x += v0 * bflo(u0.x);
        acc.y += v0 * bfhi(u0.x);
        acc.z += v0 * bflo(u0.y);
        acc.w += v0 * bfhi(u0.y);
    }
    float dr = dinv[r];
    float4 bb = *(const float4*)(bias + lane * 4);
    float4 o;
    o.x = fmaxf(dr * acc.x + bb.x, 0.f);
    o.y = fmaxf(dr * acc.y + bb.y, 0.f);
    o.z = fmaxf(dr * acc.z + bb.z, 0.f);
    o.w = fmaxf(dr * acc.w + bb.w, 0.f);
    *(float4*)(out + (long)r * DF + lane * 4) = o;
}

extern "C" void kernel_launch(void* const* d_in, const int* in_sizes, int n_in,
                              void* d_out, int out_size, void* d_ws, size_t ws_size,
                              hipStream_t stream) {
    const float* x   = (const float*)d_in[0];
    const int* erow  = (const int*)d_in[1];
    const int* ecol  = (const int*)d_in[2];
    const float* ev  = (const float*)d_in[3];
    const float* w   = (const float*)d_in[4];
    const float* b   = (const float*)d_in[5];
    float* out = (float*)d_out;

    int N = in_sizes[0] / DF;
    int E = in_sizes[1];

    char* ws = (char*)d_ws;
    size_t Na  = (((size_t)N * 4) + 255) & ~(size_t)255;        // N*4 aligned
    size_t RSa = (((size_t)(N + 1) * 4) + 255) & ~(size_t)255;  // (N+1)*4 aligned
    size_t Ea  = (((size_t)E * 4) + 255) & ~(size_t)255;        // E*4 aligned

    int*   cnt    = (int*)  (ws);
    float* dinv   = (float*)(ws + Na);
    int*   rstart = (int*)  (ws + 2 * Na);
    int2*  scv    = (int2*) (ws + 2 * Na + RSa);
    // rank and h share a region: rank dead after scatter, h born at gemm.
    char*  un     = ws + 2 * Na + RSa + 2 * Ea;
    int*   rank   = (int*)un;
    unsigned short* h = (unsigned short*)un;
    // total: 2*Na + RSa + 2*Ea + max(Ea, N*DF*2) ~= 78.0 MB (fit proven in R1)

    hipMemsetAsync(cnt, 0, Na, stream);

    hist_rank_kernel<<<(E + 255) / 256, 256, 0, stream>>>(erow, cnt, rank, E);
    scan_kernel<<<1, 1024, 0, stream>>>(cnt, rstart, N);
    scatter_kernel<<<(E + 255) / 256, 256, 0, stream>>>(erow, ecol, ev, rstart, rank, scv, E);
    degsum_kernel<<<(N + 255) / 256, 256, 0, stream>>>(scv, rstart, dinv, N);
    gemm_kernel<<<dim3((N + BM - 1) / BM, DF / BN), 256, 0, stream>>>(x, w, dinv, h, N);
    agg_kernel<<<(N + 3) / 4, 256, 0, stream>>>(h, rstart, scv, dinv, b, out, N);
}

// Round 3
// 692.191 us; speedup vs baseline: 1.7635x; 1.3648x over previous
//
#include <hip/hip_runtime.h>
#include <hip/hip_bf16.h>

// GCN layer: out = relu( (D^-1/2 A D^-1/2) (x @ w) + b )
//
// R3:
//  - gemm: bf16 MFMA (16x16x32), 128x128 tile, BK=32. fp32->bf16 conversion
//    fused into LDS staging; w transposed once (256KB, reuses cnt's slot) so
//    B fragments are contiguous ds_read_b128. dinv[c] applied in epilogue.
//  - agg: split-wave gather (lanes 0-31 even edges, 32-63 odd), uint4 loads
//    (8 features/lane), unroll 4 -> 8 edges / 4KB in flight per wave (R2 was
//    2KB, latency-bound at 48% HBM). __shfl_xor(32) merge, float4 stores.
//  - scan: 3-phase multi-block (R2's single-block per-thread-contiguous scan
//    was uncoalesced and serialized on one CU).
//  - hist: kept (3.2M atomics ~ irreducible; gfx950 atomics are HBM-side RMW
//    past L2 — the XCD coherence point; R1 WRITE_SIZE = 32B/atomic proves it).

#define DF 256   // D_FEAT == FILTERS == 256

typedef __attribute__((ext_vector_type(8))) short short8;  // 8 x bf16
typedef __attribute__((ext_vector_type(4))) float f32x4;

__device__ __forceinline__ unsigned short f2bf(float f) {
    unsigned int u = __float_as_uint(f);
    unsigned int r = (u + 0x7fffu + ((u >> 16) & 1u)) >> 16;  // RNE
    return (unsigned short)r;
}
__device__ __forceinline__ unsigned int pack2(float a, float b) {
    return (unsigned)f2bf(a) | ((unsigned)f2bf(b) << 16);
}
__device__ __forceinline__ float bflo(unsigned int u) { return __uint_as_float(u << 16); }
__device__ __forceinline__ float bfhi(unsigned int u) { return __uint_as_float(u & 0xffff0000u); }

// rank[e] = position of edge e within its row; cnt[r] = degree count
__global__ void hist_rank_kernel(const int* __restrict__ row, int* __restrict__ cnt,
                                 int* __restrict__ rank, int E) {
    int e = blockIdx.x * blockDim.x + threadIdx.x;
    if (e < E) rank[e] = atomicAdd(&cnt[row[e]], 1);
}

// ---- 3-phase exclusive scan of cnt[0..N) -> row_start[0..N] ----
__global__ __launch_bounds__(256) void scan1_kernel(const int* __restrict__ cnt,
                                                    int* __restrict__ bsum, int N) {
    __shared__ int red[256];
    int t = threadIdx.x;
    int base = blockIdx.x * 1024 + t * 4;
    int s = 0;
    if (base + 3 < N) {
        int4 v = *(const int4*)(cnt + base);
        s = v.x + v.y + v.z + v.w;
    } else {
        for (int k = 0; k < 4; ++k) if (base + k < N) s += cnt[base + k];
    }
    red[t] = s;
    __syncthreads();
    for (int off = 128; off > 0; off >>= 1) {
        if (t < off) red[t] += red[t + off];
        __syncthreads();
    }
    if (t == 0) bsum[blockIdx.x] = red[0];
}

// single block: exclusive scan of bsum[0..B) (B<=256), total -> row_start[N]
__global__ __launch_bounds__(256) void scan2_kernel(const int* __restrict__ bsum,
                                                    int* __restrict__ bpre,
                                                    int* __restrict__ row_start, int B, int N) {
    __shared__ int ps[256];
    int t = threadIdx.x;
    int v = (t < B) ? bsum[t] : 0;
    ps[t] = v;
    __syncthreads();
    for (int off = 1; off < 256; off <<= 1) {
        int u = (t >= off) ? ps[t - off] : 0;
        __syncthreads();
        ps[t] += u;
        __syncthreads();
    }
    if (t < B) bpre[t] = ps[t] - v;
    if (t == 255) row_start[N] = ps[255];
}

__global__ __launch_bounds__(256) void scan3_kernel(const int* __restrict__ cnt,
                                                    const int* __restrict__ bpre,
                                                    int* __restrict__ row_start, int N) {
    __shared__ int ps[256];
    int t = threadIdx.x;
    int base = blockIdx.x * 1024 + t * 4;
    int v0 = 0, v1 = 0, v2 = 0, v3 = 0;
    if (base + 3 < N) {
        int4 v = *(const int4*)(cnt + base);
        v0 = v.x; v1 = v.y; v2 = v.z; v3 = v.w;
    } else {
        if (base < N) v0 = cnt[base];
        if (base + 1 < N) v1 = cnt[base + 1];
        if (base + 2 < N) v2 = cnt[base + 2];
        if (base + 3 < N) v3 = cnt[base + 3];
    }
    int tsum = v0 + v1 + v2 + v3;
    ps[t] = tsum;
    __syncthreads();
    for (int off = 1; off < 256; off <<= 1) {
        int u = (t >= off) ? ps[t - off] : 0;
        __syncthreads();
        ps[t] += u;
        __syncthreads();
    }
    int pre = bpre[blockIdx.x] + ps[t] - tsum;
    if (base < N) row_start[base] = pre;
    if (base + 1 < N) row_start[base + 1] = pre + v0;
    if (base + 2 < N) row_start[base + 2] = pre + v0 + v1;
    if (base + 3 < N) row_start[base + 3] = pre + v0 + v1 + v2;
}

// Atomic-free scatter: p = row_start[row] + rank; pack (col, raw val) as int2.
__global__ void scatter_kernel(const int* __restrict__ row, const int* __restrict__ col,
                               const float* __restrict__ vals, const int* __restrict__ row_start,
                               const int* __restrict__ rank, int2* __restrict__ scv, int E) {
    int e = blockIdx.x * blockDim.x + threadIdx.x;
    if (e < E) {
        int r = row[e];
        int p = row_start[r] + rank[e];
        scv[p] = make_int2(col[e], __float_as_int(vals[e]));
    }
}

// deg[r] = sum of raw vals over the contiguous CSR segment; dinv fused.
__global__ void degsum_kernel(const int2* __restrict__ scv, const int* __restrict__ row_start,
                              float* __restrict__ dinv, int N) {
    int r = blockIdx.x * blockDim.x + threadIdx.x;
    if (r < N) {
        int s = row_start[r], e = row_start[r + 1];
        float d = 0.f;
        for (int i = s; i < e; ++i) d += __int_as_float(scv[i].y);
        dinv[r] = (d > 0.f) ? (1.0f / sqrtf(d)) : 0.f;
    }
}

// w[256][256] -> wT[256][256] (one-time, 256 KB)
__global__ __launch_bounds__(256) void transpose_kernel(const float* __restrict__ w,
                                                        float* __restrict__ wT) {
    __shared__ float tile[32][33];
    int bx = blockIdx.x * 32, by = blockIdx.y * 32;
    int tx = threadIdx.x, ty = threadIdx.y;  // dim(32,8)
    for (int j = ty; j < 32; j += 8) tile[j][tx] = w[(by + j) * DF + bx + tx];
    __syncthreads();
    for (int j = ty; j < 32; j += 8) wT[(bx + j) * DF + by + tx] = tile[tx][j];
}

// MFMA bf16 GEMM: h'[r,:] = bf16( dinv[r] * (x[r,:] @ w) )
// 128x128 tile, BK=32, 4 waves in 2x2, each wave 64x64 = 4x4 MFMA 16x16x32.
__global__ __launch_bounds__(256) void gemm_kernel(const float* __restrict__ x,
                                                   const float* __restrict__ wT,
                                                   const float* __restrict__ dinv,
                                                   unsigned short* __restrict__ h, int N) {
    __shared__ unsigned short Al[128 * 32];
    __shared__ unsigned short Bl[128 * 32];
    int tid = threadIdx.x;
    int by = blockIdx.x, bx = blockIdx.y;
    int wv = tid >> 6, lane = tid & 63;
    int wr = wv >> 1, wc = wv & 1;
    int q = lane >> 4, mi = lane & 15;

    f32x4 acc[4][4];
#pragma unroll
    for (int i = 0; i < 4; ++i)
#pragma unroll
        for (int j = 0; j < 4; ++j) acc[i][j] = (f32x4){0.f, 0.f, 0.f, 0.f};

    int srow = tid >> 1;           // 0..127
    int sseg = (tid & 1) * 16;     // k offset 0 or 16
    int axrow = by * 128 + srow; if (axrow >= N) axrow = N - 1;
    const float* ax = x + (long)axrow * DF + sseg;
    const float* bxp = wT + (long)(bx * 128 + srow) * DF + sseg;
    unsigned short* Aw = &Al[srow * 32 + sseg];
    unsigned short* Bw = &Bl[srow * 32 + sseg];

    for (int kk = 0; kk < DF; kk += 32) {
        float4 a0 = *(const float4*)(ax + kk);
        float4 a1 = *(const float4*)(ax + kk + 4);
        float4 a2 = *(const float4*)(ax + kk + 8);
        float4 a3 = *(const float4*)(ax + kk + 12);
        float4 b0 = *(const float4*)(bxp + kk);
        float4 b1 = *(const float4*)(bxp + kk + 4);
        float4 b2 = *(const float4*)(bxp + kk + 8);
        float4 b3 = *(const float4*)(bxp + kk + 12);
        __syncthreads();   // previous iteration's frag reads complete
        uint4 pa, pb;
        pa.x = pack2(a0.x, a0.y); pa.y = pack2(a0.z, a0.w);
        pa.z = pack2(a1.x, a1.y); pa.w = pack2(a1.z, a1.w);
        *(uint4*)Aw = pa;
        pa.x = pack2(a2.x, a2.y); pa.y = pack2(a2.z, a2.w);
        pa.z = pack2(a3.x, a3.y); pa.w = pack2(a3.z, a3.w);
        *(uint4*)(Aw + 8) = pa;
        pb.x = pack2(b0.x, b0.y); pb.y = pack2(b0.z, b0.w);
        pb.z = pack2(b1.x, b1.y); pb.w = pack2(b1.z, b1.w);
        *(uint4*)Bw = pb;
        pb.x = pack2(b2.x, b2.y); pb.y = pack2(b2.z, b2.w);
        pb.z = pack2(b3.x, b3.y); pb.w = pack2(b3.z, b3.w);
        *(uint4*)(Bw + 8) = pb;
        __syncthreads();   // tiles ready

        short8 af[4], bf[4];
#pragma unroll
        for (int i = 0; i < 4; ++i)
            af[i] = *(const short8*)&Al[(wr * 64 + i * 16 + mi) * 32 + q * 8];
#pragma unroll
        for (int j = 0; j < 4; ++j)
            bf[j] = *(const short8*)&Bl[(wc * 64 + j * 16 + mi) * 32 + q * 8];
#pragma unroll
        for (int i = 0; i < 4; ++i)
#pragma unroll
            for (int j = 0; j < 4; ++j)
                acc[i][j] = __builtin_amdgcn_mfma_f32_16x16x32_bf16(af[i], bf[j], acc[i][j], 0, 0, 0);
    }

    // C/D layout: col = lane&15, row = (lane>>4)*4 + reg   [verified m89/m91]
#pragma unroll
    for (int i = 0; i < 4; ++i) {
        int base_row = by * 128 + wr * 64 + i * 16 + q * 4;
#pragma unroll
        for (int r = 0; r < 4; ++r) {
            int rg = base_row + r;
            if (rg < N) {
                float dv = dinv[rg];
#pragma unroll
                for (int j = 0; j < 4; ++j) {
                    int cg = bx * 128 + wc * 64 + j * 16 + mi;
                    h[(long)rg * DF + cg] = f2bf(dv * acc[i][j][r]);
                }
            }
        }
    }
}

// One wave per node. Split-wave: lanes 0-31 even edges, 32-63 odd edges;
// each lane owns 8 features ((lane&31)*8..+8) via one uint4 (16B) load.
// Unroll 4 -> 8 edges / 4KB in flight per wave. __shfl_xor(32) merge.
__global__ __launch_bounds__(256) void agg_kernel(const unsigned short* __restrict__ h,
                                                  const int* __restrict__ row_start,
                                                  const int2* __restrict__ scv,
                                                  const float* __restrict__ dinv,
                                                  const float* __restrict__ bias,
                                                  float* __restrict__ out, int N) {
    int wave = threadIdx.x >> 6;
    int lane = threadIdx.x & 63;
    int r = blockIdx.x * 4 + wave;
    if (r >= N) return;
    int half = lane >> 5;
    int fl = (lane & 31) * 8;
    int s = row_start[r], e = row_start[r + 1];
    float a0 = 0, a1 = 0, a2 = 0, a3 = 0, a4 = 0, a5 = 0, a6 = 0, a7 = 0;
    const unsigned short* hp = h + fl;
    int i = s + half;
    for (; i + 6 < e; i += 8) {
        int2 e0 = scv[i], e1 = scv[i + 2], e2 = scv[i + 4], e3 = scv[i + 6];
        uint4 u0 = *(const uint4*)(hp + (long)e0.x * DF);
        uint4 u1 = *(const uint4*)(hp + (long)e1.x * DF);
        uint4 u2 = *(const uint4*)(hp + (long)e2.x * DF);
        uint4 u3 = *(const uint4*)(hp + (long)e3.x * DF);
        float v0 = __int_as_float(e0.y), v1 = __int_as_float(e1.y);
        float v2 = __int_as_float(e2.y), v3 = __int_as_float(e3.y);
        a0 += v0 * bflo(u0.x) + v1 * bflo(u1.x) + v2 * bflo(u2.x) + v3 * bflo(u3.x);
        a1 += v0 * bfhi(u0.x) + v1 * bfhi(u1.x) + v2 * bfhi(u2.x) + v3 * bfhi(u3.x);
        a2 += v0 * bflo(u0.y) + v1 * bflo(u1.y) + v2 * bflo(u2.y) + v3 * bflo(u3.y);
        a3 += v0 * bfhi(u0.y) + v1 * bfhi(u1.y) + v2 * bfhi(u2.y) + v3 * bfhi(u3.y);
        a4 += v0 * bflo(u0.z) + v1 * bflo(u1.z) + v2 * bflo(u2.z) + v3 * bflo(u3.z);
        a5 += v0 * bfhi(u0.z) + v1 * bfhi(u1.z) + v2 * bfhi(u2.z) + v3 * bfhi(u3.z);
        a6 += v0 * bflo(u0.w) + v1 * bflo(u1.w) + v2 * bflo(u2.w) + v3 * bflo(u3.w);
        a7 += v0 * bfhi(u0.w) + v1 * bfhi(u1.w) + v2 * bfhi(u2.w) + v3 * bfhi(u3.w);
    }
    for (; i < e; i += 2) {
        int2 e0 = scv[i];
        float v0 = __int_as_float(e0.y);
        uint4 u0 = *(const uint4*)(hp + (long)e0.x * DF);
        a0 += v0 * bflo(u0.x); a1 += v0 * bfhi(u0.x);
        a2 += v0 * bflo(u0.y); a3 += v0 * bfhi(u0.y);
        a4 += v0 * bflo(u0.z); a5 += v0 * bfhi(u0.z);
        a6 += v0 * bflo(u0.w); a7 += v0 * bfhi(u0.w);
    }
    a0 += __shfl_xor(a0, 32); a1 += __shfl_xor(a1, 32);
    a2 += __shfl_xor(a2, 32); a3 += __shfl_xor(a3, 32);
    a4 += __shfl_xor(a4, 32); a5 += __shfl_xor(a5, 32);
    a6 += __shfl_xor(a6, 32); a7 += __shfl_xor(a7, 32);
    if (half == 0) {
        float dr = dinv[r];
        float4 b0 = *(const float4*)(bias + fl);
        float4 b1 = *(const float4*)(bias + fl + 4);
        float4 o0, o1;
        o0.x = fmaxf(fmaf(dr, a0, b0.x), 0.f);
        o0.y = fmaxf(fmaf(dr, a1, b0.y), 0.f);
        o0.z = fmaxf(fmaf(dr, a2, b0.z), 0.f);
        o0.w = fmaxf(fmaf(dr, a3, b0.w), 0.f);
        o1.x = fmaxf(fmaf(dr, a4, b1.x), 0.f);
        o1.y = fmaxf(fmaf(dr, a5, b1.y), 0.f);
        o1.z = fmaxf(fmaf(dr, a6, b1.z), 0.f);
        o1.w = fmaxf(fmaf(dr, a7, b1.w), 0.f);
        *(float4*)(out + (long)r * DF + fl) = o0;
        *(float4*)(out + (long)r * DF + fl + 4) = o1;
    }
}

extern "C" void kernel_launch(void* const* d_in, const int* in_sizes, int n_in,
                              void* d_out, int out_size, void* d_ws, size_t ws_size,
                              hipStream_t stream) {
    const float* x   = (const float*)d_in[0];
    const int* erow  = (const int*)d_in[1];
    const int* ecol  = (const int*)d_in[2];
    const float* ev  = (const float*)d_in[3];
    const float* w   = (const float*)d_in[4];
    const float* b   = (const float*)d_in[5];
    float* out = (float*)d_out;

    int N = in_sizes[0] / DF;
    int E = in_sizes[1];

    char* ws = (char*)d_ws;
    size_t Na  = (((size_t)N * 4) + 255) & ~(size_t)255;
    size_t RSa = (((size_t)(N + 1) * 4) + 255) & ~(size_t)255;
    size_t Ea  = (((size_t)E * 4) + 255) & ~(size_t)255;

    // Lifetimes: cnt dies after scan3 -> wT reuses its slot (256KB <= Na).
    // rank dies after scatter; h born at gemm -> share region `un`.
    // bsum/bpre live only during scan -> parked at un+16MB (past rank's 12.8MB,
    // dead before h is born).
    int*   cnt    = (int*)  (ws);
    float* wT     = (float*)(ws);                 // after scan3
    float* dinv   = (float*)(ws + Na);
    int*   rstart = (int*)  (ws + 2 * Na);
    int2*  scv    = (int2*) (ws + 2 * Na + RSa);
    char*  un     = ws + 2 * Na + RSa + 2 * Ea;
    int*   rank   = (int*)un;
    unsigned short* h = (unsigned short*)un;
    int*   bsum   = (int*)(un + 16000000);
    int*   bpre   = (int*)(un + 16000000 + 4096);

    int B1 = (N + 1023) / 1024;  // 98 for N=100k (scan2 supports B1<=256)

    hipMemsetAsync(cnt, 0, Na, stream);

    hist_rank_kernel<<<(E + 255) / 256, 256, 0, stream>>>(erow, cnt, rank, E);
    scan1_kernel<<<B1, 256, 0, stream>>>(cnt, bsum, N);
    scan2_kernel<<<1, 256, 0, stream>>>(bsum, bpre, rstart, B1, N);
    scan3_kernel<<<B1, 256, 0, stream>>>(cnt, bpre, rstart, N);
    scatter_kernel<<<(E + 255) / 256, 256, 0, stream>>>(erow, ecol, ev, rstart, rank, scv, E);
    degsum_kernel<<<(N + 255) / 256, 256, 0, stream>>>(scv, rstart, dinv, N);
    transpose_kernel<<<dim3(8, 8), dim3(32, 8), 0, stream>>>(w, wT);
    gemm_kernel<<<dim3((N + 127) / 128, DF / 128), 256, 0, stream>>>(x, wT, dinv, h, N);
    agg_kernel<<<(N + 3) / 4, 256, 0, stream>>>(h, rstart, scv, dinv, b, out, N);
}

// Round 4
// 691.047 us; speedup vs baseline: 1.7664x; 1.0017x over previous
//
#include <hip/hip_runtime.h>
#include <hip/hip_bf16.h>

// GCN layer: out = relu( (D^-1/2 A D^-1/2) (x @ w) + b )
//
// R4: per-XCD histogram planes + workgroup-scope atomics.
//   R1 evidence: device-scope atomicAdd = 32B RMW past L2 (WRITE_SIZE 32B/op,
//   ~23 G ops/s) because per-XCD L2s are non-coherent. A histogram doesn't
//   need cross-XCD coherence: each XCD atomically updates its OWN plane
//   cntx[xcd][row] (xcd from s_getreg(HW_REG_XCC_ID), wave-uniform) with
//   __HIP_MEMORY_SCOPE_WORKGROUP, which executes the RMW in the local TCC
//   (shared by all CUs of the XCD -> atomic across workgroups there).
//   rank[e] = (xcd<<27) | local_rank; scan emits basex[xcd][row] prefix bases
//   so scatter stays atomic-free: p = basex[xcd][r] + local_rank.
// agg unchanged: at a ~4 TB/s past-L2 gather ceiling (R2->R3: 2x MLP changed
//   nothing; FETCH 762 MB invariant). fp8/int8 h fails error budget (8x/6x
//   current 0.0078 absmax > 0.029 threshold).

#define DF 256   // D_FEAT == FILTERS == 256

typedef __attribute__((ext_vector_type(8))) short short8;  // 8 x bf16
typedef __attribute__((ext_vector_type(4))) float f32x4;

__device__ __forceinline__ unsigned short f2bf(float f) {
    unsigned int u = __float_as_uint(f);
    unsigned int r = (u + 0x7fffu + ((u >> 16) & 1u)) >> 16;  // RNE
    return (unsigned short)r;
}
__device__ __forceinline__ unsigned int pack2(float a, float b) {
    return (unsigned)f2bf(a) | ((unsigned)f2bf(b) << 16);
}
__device__ __forceinline__ float bflo(unsigned int u) { return __uint_as_float(u << 16); }
__device__ __forceinline__ float bfhi(unsigned int u) { return __uint_as_float(u & 0xffff0000u); }

__device__ __forceinline__ unsigned xcc_id() {
    unsigned x;
    asm volatile("s_getreg_b32 %0, hwreg(HW_REG_XCC_ID)" : "=s"(x));
    return x & 7u;
}

// Per-XCD-plane histogram. cntx has 8 planes of Np ints; local L2 atomics.
__global__ void hist_rank_kernel(const int* __restrict__ row, int* __restrict__ cntx,
                                 int* __restrict__ rank, int Np, int E) {
    int e = blockIdx.x * blockDim.x + threadIdx.x;
    if (e < E) {
        unsigned x = xcc_id();
        int r = row[e];
        int lr = __hip_atomic_fetch_add(&cntx[(size_t)x * Np + r], 1,
                                        __ATOMIC_RELAXED, __HIP_MEMORY_SCOPE_WORKGROUP);
        rank[e] = lr | (int)(x << 27);
    }
}

// ---- 3-phase exclusive scan over per-row totals (sum of 8 planes) ----
__global__ __launch_bounds__(256) void scan1_kernel(const int* __restrict__ cntx,
                                                    int* __restrict__ bsum, int Np, int N) {
    __shared__ int red[256];
    int t = threadIdx.x;
    int base = blockIdx.x * 1024 + t * 4;
    int s = 0;
    if (base + 3 < N) {
        for (int x = 0; x < 8; ++x) {
            int4 v = *(const int4*)(cntx + (size_t)x * Np + base);
            s += v.x + v.y + v.z + v.w;
        }
    } else {
        for (int x = 0; x < 8; ++x)
            for (int k = 0; k < 4; ++k)
                if (base + k < N) s += cntx[(size_t)x * Np + base + k];
    }
    red[t] = s;
    __syncthreads();
    for (int off = 128; off > 0; off >>= 1) {
        if (t < off) red[t] += red[t + off];
        __syncthreads();
    }
    if (t == 0) bsum[blockIdx.x] = red[0];
}

__global__ __launch_bounds__(256) void scan2_kernel(const int* __restrict__ bsum,
                                                    int* __restrict__ bpre,
                                                    int* __restrict__ row_start, int B, int N) {
    __shared__ int ps[256];
    int t = threadIdx.x;
    int v = (t < B) ? bsum[t] : 0;
    ps[t] = v;
    __syncthreads();
    for (int off = 1; off < 256; off <<= 1) {
        int u = (t >= off) ? ps[t - off] : 0;
        __syncthreads();
        ps[t] += u;
        __syncthreads();
    }
    if (t < B) bpre[t] = ps[t] - v;
    if (t == 255) row_start[N] = ps[255];
}

// rstart[r] + basex[x][r] = rstart[r] + sum_{x'<x} cntx[x'][r]
__global__ __launch_bounds__(256) void scan3_kernel(const int* __restrict__ cntx,
                                                    const int* __restrict__ bpre,
                                                    int* __restrict__ row_start,
                                                    int* __restrict__ basex, int Np, int N) {
    __shared__ int ps[256];
    int t = threadIdx.x;
    int base = blockIdx.x * 1024 + t * 4;
    int v[8][4];
    if (base + 3 < N) {
        for (int x = 0; x < 8; ++x) {
            int4 q = *(const int4*)(cntx + (size_t)x * Np + base);
            v[x][0] = q.x; v[x][1] = q.y; v[x][2] = q.z; v[x][3] = q.w;
        }
    } else {
        for (int x = 0; x < 8; ++x)
            for (int k = 0; k < 4; ++k)
                v[x][k] = (base + k < N) ? cntx[(size_t)x * Np + base + k] : 0;
    }
    int tot[4];
    for (int k = 0; k < 4; ++k) {
        int s = 0;
        for (int x = 0; x < 8; ++x) s += v[x][k];
        tot[k] = s;
    }
    int tsum = tot[0] + tot[1] + tot[2] + tot[3];
    ps[t] = tsum;
    __syncthreads();
    for (int off = 1; off < 256; off <<= 1) {
        int u = (t >= off) ? ps[t - off] : 0;
        __syncthreads();
        ps[t] += u;
        __syncthreads();
    }
    int pre = bpre[blockIdx.x] + ps[t] - tsum;
    int acc[4];
    acc[0] = pre;
    acc[1] = acc[0] + tot[0];
    acc[2] = acc[1] + tot[1];
    acc[3] = acc[2] + tot[2];
    if (base + 3 < N) {
        *(int4*)(row_start + base) = make_int4(acc[0], acc[1], acc[2], acc[3]);
        for (int x = 0; x < 8; ++x) {
            *(int4*)(basex + (size_t)x * Np + base) = make_int4(acc[0], acc[1], acc[2], acc[3]);
            for (int k = 0; k < 4; ++k) acc[k] += v[x][k];
        }
    } else {
        for (int k = 0; k < 4; ++k) if (base + k < N) row_start[base + k] = acc[k];
        for (int x = 0; x < 8; ++x)
            for (int k = 0; k < 4; ++k) {
                if (base + k < N) basex[(size_t)x * Np + base + k] = acc[k];
                acc[k] += v[x][k];
            }
    }
}

// Atomic-free scatter: p = basex[xcd][row] + local_rank.
__global__ void scatter_kernel(const int* __restrict__ row, const int* __restrict__ col,
                               const float* __restrict__ vals, const int* __restrict__ basex,
                               const int* __restrict__ rank, int2* __restrict__ scv,
                               int Np, int E) {
    int e = blockIdx.x * blockDim.x + threadIdx.x;
    if (e < E) {
        int r = row[e];
        int pk = rank[e];
        int x = ((unsigned)pk) >> 27;
        int lr = pk & 0x07FFFFFF;
        int p = basex[(size_t)x * Np + r] + lr;
        scv[p] = make_int2(col[e], __float_as_int(vals[e]));
    }
}

// deg[r] = sum of raw vals over the contiguous CSR segment; dinv fused.
__global__ void degsum_kernel(const int2* __restrict__ scv, const int* __restrict__ row_start,
                              float* __restrict__ dinv, int N) {
    int r = blockIdx.x * blockDim.x + threadIdx.x;
    if (r < N) {
        int s = row_start[r], e = row_start[r + 1];
        float d = 0.f;
        for (int i = s; i < e; ++i) d += __int_as_float(scv[i].y);
        dinv[r] = (d > 0.f) ? (1.0f / sqrtf(d)) : 0.f;
    }
}

// w[256][256] -> wT[256][256] (one-time, 256 KB)
__global__ __launch_bounds__(256) void transpose_kernel(const float* __restrict__ w,
                                                        float* __restrict__ wT) {
    __shared__ float tile[32][33];
    int bx = blockIdx.x * 32, by = blockIdx.y * 32;
    int tx = threadIdx.x, ty = threadIdx.y;  // dim(32,8)
    for (int j = ty; j < 32; j += 8) tile[j][tx] = w[(by + j) * DF + bx + tx];
    __syncthreads();
    for (int j = ty; j < 32; j += 8) wT[(bx + j) * DF + by + tx] = tile[tx][j];
}

// MFMA bf16 GEMM: h'[r,:] = bf16( dinv[r] * (x[r,:] @ w) )
// 128x128 tile, BK=32, 4 waves in 2x2, each wave 64x64 = 4x4 MFMA 16x16x32.
__global__ __launch_bounds__(256) void gemm_kernel(const float* __restrict__ x,
                                                   const float* __restrict__ wT,
                                                   const float* __restrict__ dinv,
                                                   unsigned short* __restrict__ h, int N) {
    __shared__ unsigned short Al[128 * 32];
    __shared__ unsigned short Bl[128 * 32];
    int tid = threadIdx.x;
    int by = blockIdx.x, bx = blockIdx.y;
    int wv = tid >> 6, lane = tid & 63;
    int wr = wv >> 1, wc = wv & 1;
    int q = lane >> 4, mi = lane & 15;

    f32x4 acc[4][4];
#pragma unroll
    for (int i = 0; i < 4; ++i)
#pragma unroll
        for (int j = 0; j < 4; ++j) acc[i][j] = (f32x4){0.f, 0.f, 0.f, 0.f};

    int srow = tid >> 1;           // 0..127
    int sseg = (tid & 1) * 16;     // k offset 0 or 16
    int axrow = by * 128 + srow; if (axrow >= N) axrow = N - 1;
    const float* ax = x + (long)axrow * DF + sseg;
    const float* bxp = wT + (long)(bx * 128 + srow) * DF + sseg;
    unsigned short* Aw = &Al[srow * 32 + sseg];
    unsigned short* Bw = &Bl[srow * 32 + sseg];

    for (int kk = 0; kk < DF; kk += 32) {
        float4 a0 = *(const float4*)(ax + kk);
        float4 a1 = *(const float4*)(ax + kk + 4);
        float4 a2 = *(const float4*)(ax + kk + 8);
        float4 a3 = *(const float4*)(ax + kk + 12);
        float4 b0 = *(const float4*)(bxp + kk);
        float4 b1 = *(const float4*)(bxp + kk + 4);
        float4 b2 = *(const float4*)(bxp + kk + 8);
        float4 b3 = *(const float4*)(bxp + kk + 12);
        __syncthreads();   // previous iteration's frag reads complete
        uint4 pa, pb;
        pa.x = pack2(a0.x, a0.y); pa.y = pack2(a0.z, a0.w);
        pa.z = pack2(a1.x, a1.y); pa.w = pack2(a1.z, a1.w);
        *(uint4*)Aw = pa;
        pa.x = pack2(a2.x, a2.y); pa.y = pack2(a2.z, a2.w);
        pa.z = pack2(a3.x, a3.y); pa.w = pack2(a3.z, a3.w);
        *(uint4*)(Aw + 8) = pa;
        pb.x = pack2(b0.x, b0.y); pb.y = pack2(b0.z, b0.w);
        pb.z = pack2(b1.x, b1.y); pb.w = pack2(b1.z, b1.w);
        *(uint4*)Bw = pb;
        pb.x = pack2(b2.x, b2.y); pb.y = pack2(b2.z, b2.w);
        pb.z = pack2(b3.x, b3.y); pb.w = pack2(b3.z, b3.w);
        *(uint4*)(Bw + 8) = pb;
        __syncthreads();   // tiles ready

        short8 af[4], bf[4];
#pragma unroll
        for (int i = 0; i < 4; ++i)
            af[i] = *(const short8*)&Al[(wr * 64 + i * 16 + mi) * 32 + q * 8];
#pragma unroll
        for (int j = 0; j < 4; ++j)
            bf[j] = *(const short8*)&Bl[(wc * 64 + j * 16 + mi) * 32 + q * 8];
#pragma unroll
        for (int i = 0; i < 4; ++i)
#pragma unroll
            for (int j = 0; j < 4; ++j)
                acc[i][j] = __builtin_amdgcn_mfma_f32_16x16x32_bf16(af[i], bf[j], acc[i][j], 0, 0, 0);
    }

    // C/D layout: col = lane&15, row = (lane>>4)*4 + reg   [verified m89/m91]
#pragma unroll
    for (int i = 0; i < 4; ++i) {
        int base_row = by * 128 + wr * 64 + i * 16 + q * 4;
#pragma unroll
        for (int r = 0; r < 4; ++r) {
            int rg = base_row + r;
            if (rg < N) {
                float dv = dinv[rg];
#pragma unroll
                for (int j = 0; j < 4; ++j) {
                    int cg = bx * 128 + wc * 64 + j * 16 + mi;
                    h[(long)rg * DF + cg] = f2bf(dv * acc[i][j][r]);
                }
            }
        }
    }
}

// One wave per node. Split-wave: lanes 0-31 even edges, 32-63 odd edges;
// each lane owns 8 features via one uint4 (16B) load. Unroll 4 -> 8 edges /
// 4KB in flight. __shfl_xor(32) merge, coalesced float4 stores.
__global__ __launch_bounds__(256) void agg_kernel(const unsigned short* __restrict__ h,
                                                  const int* __restrict__ row_start,
                                                  const int2* __restrict__ scv,
                                                  const float* __restrict__ dinv,
                                                  const float* __restrict__ bias,
                                                  float* __restrict__ out, int N) {
    int wave = threadIdx.x >> 6;
    int lane = threadIdx.x & 63;
    int r = blockIdx.x * 4 + wave;
    if (r >= N) return;
    int half = lane >> 5;
    int fl = (lane & 31) * 8;
    int s = row_start[r], e = row_start[r + 1];
    float a0 = 0, a1 = 0, a2 = 0, a3 = 0, a4 = 0, a5 = 0, a6 = 0, a7 = 0;
    const unsigned short* hp = h + fl;
    int i = s + half;
    for (; i + 6 < e; i += 8) {
        int2 e0 = scv[i], e1 = scv[i + 2], e2 = scv[i + 4], e3 = scv[i + 6];
        uint4 u0 = *(const uint4*)(hp + (long)e0.x * DF);
        uint4 u1 = *(const uint4*)(hp + (long)e1.x * DF);
        uint4 u2 = *(const uint4*)(hp + (long)e2.x * DF);
        uint4 u3 = *(const uint4*)(hp + (long)e3.x * DF);
        float v0 = __int_as_float(e0.y), v1 = __int_as_float(e1.y);
        float v2 = __int_as_float(e2.y), v3 = __int_as_float(e3.y);
        a0 += v0 * bflo(u0.x) + v1 * bflo(u1.x) + v2 * bflo(u2.x) + v3 * bflo(u3.x);
        a1 += v0 * bfhi(u0.x) + v1 * bfhi(u1.x) + v2 * bfhi(u2.x) + v3 * bfhi(u3.x);
        a2 += v0 * bflo(u0.y) + v1 * bflo(u1.y) + v2 * bflo(u2.y) + v3 * bflo(u3.y);
        a3 += v0 * bfhi(u0.y) + v1 * bfhi(u1.y) + v2 * bfhi(u2.y) + v3 * bfhi(u3.y);
        a4 += v0 * bflo(u0.z) + v1 * bflo(u1.z) + v2 * bflo(u2.z) + v3 * bflo(u3.z);
        a5 += v0 * bfhi(u0.z) + v1 * bfhi(u1.z) + v2 * bfhi(u2.z) + v3 * bfhi(u3.z);
        a6 += v0 * bflo(u0.w) + v1 * bflo(u1.w) + v2 * bflo(u2.w) + v3 * bflo(u3.w);
        a7 += v0 * bfhi(u0.w) + v1 * bfhi(u1.w) + v2 * bfhi(u2.w) + v3 * bfhi(u3.w);
    }
    for (; i < e; i += 2) {
        int2 e0 = scv[i];
        float v0 = __int_as_float(e0.y);
        uint4 u0 = *(const uint4*)(hp + (long)e0.x * DF);
        a0 += v0 * bflo(u0.x); a1 += v0 * bfhi(u0.x);
        a2 += v0 * bflo(u0.y); a3 += v0 * bfhi(u0.y);
        a4 += v0 * bflo(u0.z); a5 += v0 * bfhi(u0.z);
        a6 += v0 * bflo(u0.w); a7 += v0 * bfhi(u0.w);
    }
    a0 += __shfl_xor(a0, 32); a1 += __shfl_xor(a1, 32);
    a2 += __shfl_xor(a2, 32); a3 += __shfl_xor(a3, 32);
    a4 += __shfl_xor(a4, 32); a5 += __shfl_xor(a5, 32);
    a6 += __shfl_xor(a6, 32); a7 += __shfl_xor(a7, 32);
    if (half == 0) {
        float dr = dinv[r];
        float4 b0 = *(const float4*)(bias + fl);
        float4 b1 = *(const float4*)(bias + fl + 4);
        float4 o0, o1;
        o0.x = fmaxf(fmaf(dr, a0, b0.x), 0.f);
        o0.y = fmaxf(fmaf(dr, a1, b0.y), 0.f);
        o0.z = fmaxf(fmaf(dr, a2, b0.z), 0.f);
        o0.w = fmaxf(fmaf(dr, a3, b0.w), 0.f);
        o1.x = fmaxf(fmaf(dr, a4, b1.x), 0.f);
        o1.y = fmaxf(fmaf(dr, a5, b1.y), 0.f);
        o1.z = fmaxf(fmaf(dr, a6, b1.z), 0.f);
        o1.w = fmaxf(fmaf(dr, a7, b1.w), 0.f);
        *(float4*)(out + (long)r * DF + fl) = o0;
        *(float4*)(out + (long)r * DF + fl + 4) = o1;
    }
}

extern "C" void kernel_launch(void* const* d_in, const int* in_sizes, int n_in,
                              void* d_out, int out_size, void* d_ws, size_t ws_size,
                              hipStream_t stream) {
    const float* x   = (const float*)d_in[0];
    const int* erow  = (const int*)d_in[1];
    const int* ecol  = (const int*)d_in[2];
    const float* ev  = (const float*)d_in[3];
    const float* w   = (const float*)d_in[4];
    const float* b   = (const float*)d_in[5];
    float* out = (float*)d_out;

    int N = in_sizes[0] / DF;
    int E = in_sizes[1];

    char* ws = (char*)d_ws;
    size_t Na  = (((size_t)N * 4) + 255) & ~(size_t)255;
    size_t RSa = (((size_t)(N + 1) * 4) + 255) & ~(size_t)255;
    size_t Ea  = (((size_t)E * 4) + 255) & ~(size_t)255;
    int Np = (int)(Na >> 2);  // plane stride in ints

    // Lifetimes (total = 2*Na + RSa + 2*Ea + max(Ea, N*512) — same as R3):
    //   wT (256KB) at ws+0.
    //   cntx (8 planes, 8*Na) ALIASES scv start: dead after scan3, scv born
    //   at scatter.
    //   rank (Ea) and h (N*512) share `un`; bsum/bpre at un+16MB; basex
    //   (8*Na) at un+17MB — alive scan3->scatter, dead before h is born.
    float* wT     = (float*)(ws);
    float* dinv   = (float*)(ws + Na);
    int*   rstart = (int*)  (ws + 2 * Na);
    int2*  scv    = (int2*) (ws + 2 * Na + RSa);
    int*   cntx   = (int*)  (ws + 2 * Na + RSa);   // alias of scv
    char*  un     = ws + 2 * Na + RSa + 2 * Ea;
    int*   rank   = (int*)un;
    unsigned short* h = (unsigned short*)un;
    int*   bsum   = (int*)(un + 16000000);
    int*   bpre   = (int*)(un + 16000000 + 4096);
    int*   basex  = (int*)(un + 17000000);

    int B1 = (N + 1023) / 1024;  // 98 for N=100k (scan2 supports <=256)

    hipMemsetAsync(cntx, 0, 8 * Na, stream);

    hist_rank_kernel<<<(E + 255) / 256, 256, 0, stream>>>(erow, cntx, rank, Np, E);
    scan1_kernel<<<B1, 256, 0, stream>>>(cntx, bsum, Np, N);
    scan2_kernel<<<1, 256, 0, stream>>>(bsum, bpre, rstart, B1, N);
    scan3_kernel<<<B1, 256, 0, stream>>>(cntx, bpre, rstart, basex, Np, N);
    scatter_kernel<<<(E + 255) / 256, 256, 0, stream>>>(erow, ecol, ev, basex, rank, scv, Np, E);
    degsum_kernel<<<(N + 255) / 256, 256, 0, stream>>>(scv, rstart, dinv, N);
    transpose_kernel<<<dim3(8, 8), dim3(32, 8), 0, stream>>>(w, wT);
    gemm_kernel<<<dim3((N + 127) / 128, DF / 128), 256, 0, stream>>>(x, wT, dinv, h, N);
    agg_kernel<<<(N + 3) / 4, 256, 0, stream>>>(h, rstart, scv, dinv, b, out, N);
}

// Round 5
// 595.873 us; speedup vs baseline: 2.0485x; 1.1597x over previous
//
#include <hip/hip_runtime.h>
#include <hip/hip_bf16.h>

// GCN layer: out = relu( (D^-1/2 A D^-1/2) (x @ w) + b )
//
// R5: atomic-free bucketed CSR-less pipeline.
//   R1/R4 evidence: gfx950 global atomic RMW ~23 G/s, write-through 32B/op,
//   scope qualifier makes no difference -> any per-edge global atomic costs
//   ~140 us. R3 scatter's random 8B writes over 25.6MB cost ~140 us more
//   (unmergeable dirty lines). Replace the whole CSR build with a 2-level
//   bucket sort (bucket = row>>7, 128 rows/bucket, ~4096 edges/bucket):
//     A1  per-block LDS bucket histogram  (no global atomics)
//     A2  column scan over blocks per bucket; A2b bucket_base scan
//     A3  scatter packed (rowlow<<17|col, val) int2; block's writes land in
//         782 short runs -> L2 merges dirty lines (unlike R3's scatter)
//     Deg block/bucket LDS float accum -> dinv (replaces strided degsum)
//     aggB block/bucket: counting-sort bucket edges into LDS, then
//          wave-per-row gather identical to R4's agg inner loop.
//   gemm (bf16 MFMA) and transpose unchanged from R4.
// agg gather itself is throughput-capped ~4 TB/s on the past-L2 path
// (R2->R3: 2x MLP changed nothing); fp8 h fails the error budget.

#define DF   256   // D_FEAT == FILTERS == 256
#define RSH  7
#define RPB  128   // rows per bucket = 1<<RSH
#define CAP  4800  // LDS edge capacity per bucket (mean 4096, sd 64 -> 11 sigma)
#define CHUNK 8192 // edges per block in A1/A3

typedef __attribute__((ext_vector_type(8))) short short8;  // 8 x bf16
typedef __attribute__((ext_vector_type(4))) float f32x4;

__device__ __forceinline__ unsigned short f2bf(float f) {
    unsigned int u = __float_as_uint(f);
    unsigned int r = (u + 0x7fffu + ((u >> 16) & 1u)) >> 16;  // RNE
    return (unsigned short)r;
}
__device__ __forceinline__ unsigned int pack2(float a, float b) {
    return (unsigned)f2bf(a) | ((unsigned)f2bf(b) << 16);
}
__device__ __forceinline__ float bflo(unsigned int u) { return __uint_as_float(u << 16); }
__device__ __forceinline__ float bfhi(unsigned int u) { return __uint_as_float(u & 0xffff0000u); }

// A1: per-block bucket histogram (NB <= 1024)
__global__ __launch_bounds__(256) void bhist_kernel(const int* __restrict__ row,
                                                    int* __restrict__ blockhist, int NB, int E) {
    __shared__ int hist[1024];
    int t = threadIdx.x;
    for (int i = t; i < NB; i += 256) hist[i] = 0;
    __syncthreads();
    int base = blockIdx.x * CHUNK;
    int end = base + CHUNK; if (end > E) end = E;
    for (int i = base + t; i < end; i += 256)
        atomicAdd(&hist[row[i] >> RSH], 1);
    __syncthreads();
    for (int i = t; i < NB; i += 256)
        blockhist[(size_t)blockIdx.x * NB + i] = hist[i];
}

// A2: per bucket (blockIdx), exclusive scan over NBLK block counts (NBLK <= 512).
// In-place: blockhist[e][b] <- sum_{e'<e} blockhist[e'][b]; total -> buckettot[b].
__global__ __launch_bounds__(256) void bscan_kernel(int* __restrict__ blockhist,
                                                    int* __restrict__ buckettot, int NB, int NBLK) {
    __shared__ int ps[256];
    int b = blockIdx.x, t = threadIdx.x;
    int e0 = 2 * t, e1 = 2 * t + 1;
    int v0 = (e0 < NBLK) ? blockhist[(size_t)e0 * NB + b] : 0;
    int v1 = (e1 < NBLK) ? blockhist[(size_t)e1 * NB + b] : 0;
    int tsum = v0 + v1;
    ps[t] = tsum;
    __syncthreads();
    for (int off = 1; off < 256; off <<= 1) {
        int v = (t >= off) ? ps[t - off] : 0;
        __syncthreads();
        ps[t] += v;
        __syncthreads();
    }
    int pre = ps[t] - tsum;  // exclusive
    if (e0 < NBLK) blockhist[(size_t)e0 * NB + b] = pre;
    if (e1 < NBLK) blockhist[(size_t)e1 * NB + b] = pre + v0;
    if (t == 255) buckettot[b] = ps[255];
}

// A2b: single block, exclusive scan of buckettot[0..NB) -> bucket_base[0..NB]
__global__ __launch_bounds__(1024) void btot_kernel(const int* __restrict__ buckettot,
                                                    int* __restrict__ bucket_base, int NB) {
    __shared__ int ps[1024];
    int t = threadIdx.x;
    int v = (t < NB) ? buckettot[t] : 0;
    ps[t] = v;
    __syncthreads();
    for (int off = 1; off < 1024; off <<= 1) {
        int u = (t >= off) ? ps[t - off] : 0;
        __syncthreads();
        ps[t] += u;
        __syncthreads();
    }
    if (t < NB) bucket_base[t] = ps[t] - v;
    if (t == 1023) bucket_base[NB] = ps[1023];
}

// A3: scatter edges into buckets. Same chunking as A1; LDS atomics only.
__global__ __launch_bounds__(256) void bscatter_kernel(const int* __restrict__ row,
                                                       const int* __restrict__ col,
                                                       const float* __restrict__ vals,
                                                       const int* __restrict__ blockhist,
                                                       const int* __restrict__ bucket_base,
                                                       int2* __restrict__ bedge, int NB, int E) {
    __shared__ int loff[1024];
    int t = threadIdx.x, blk = blockIdx.x;
    for (int i = t; i < NB; i += 256)
        loff[i] = bucket_base[i] + blockhist[(size_t)blk * NB + i];
    __syncthreads();
    int base = blk * CHUNK;
    int end = base + CHUNK; if (end > E) end = E;
    for (int i = base + t; i < end; i += 256) {
        int r = row[i];
        int p = atomicAdd(&loff[r >> RSH], 1);
        bedge[p] = make_int2(((r & (RPB - 1)) << 17) | col[i], __float_as_int(vals[i]));
    }
}

// Deg: block per bucket; LDS float accumulators; fused dinv.
__global__ __launch_bounds__(256) void deg_kernel(const int2* __restrict__ bedge,
                                                  const int* __restrict__ bucket_base,
                                                  float* __restrict__ dinv, int N) {
    __shared__ float acc[RPB];
    int b = blockIdx.x, t = threadIdx.x;
    if (t < RPB) acc[t] = 0.f;
    __syncthreads();
    int s = bucket_base[b], e = bucket_base[b + 1];
    for (int i = s + t; i < e; i += 256) {
        int2 ed = bedge[i];
        atomicAdd(&acc[ed.x >> 17], __int_as_float(ed.y));
    }
    __syncthreads();
    if (t < RPB) {
        int r = b * RPB + t;
        if (r < N) {
            float d = acc[t];
            dinv[r] = (d > 0.f) ? (1.0f / sqrtf(d)) : 0.f;
        }
    }
}

// w[256][256] -> wT[256][256] (one-time, 256 KB)
__global__ __launch_bounds__(256) void transpose_kernel(const float* __restrict__ w,
                                                        float* __restrict__ wT) {
    __shared__ float tile[32][33];
    int bx = blockIdx.x * 32, by = blockIdx.y * 32;
    int tx = threadIdx.x, ty = threadIdx.y;  // dim(32,8)
    for (int j = ty; j < 32; j += 8) tile[j][tx] = w[(by + j) * DF + bx + tx];
    __syncthreads();
    for (int j = ty; j < 32; j += 8) wT[(bx + j) * DF + by + tx] = tile[tx][j];
}

// MFMA bf16 GEMM: h'[r,:] = bf16( dinv[r] * (x[r,:] @ w) )
// 128x128 tile, BK=32, 4 waves in 2x2, each wave 64x64 = 4x4 MFMA 16x16x32.
__global__ __launch_bounds__(256) void gemm_kernel(const float* __restrict__ x,
                                                   const float* __restrict__ wT,
                                                   const float* __restrict__ dinv,
                                                   unsigned short* __restrict__ h, int N) {
    __shared__ unsigned short Al[128 * 32];
    __shared__ unsigned short Bl[128 * 32];
    int tid = threadIdx.x;
    int by = blockIdx.x, bx = blockIdx.y;
    int wv = tid >> 6, lane = tid & 63;
    int wr = wv >> 1, wc = wv & 1;
    int q = lane >> 4, mi = lane & 15;

    f32x4 acc[4][4];
#pragma unroll
    for (int i = 0; i < 4; ++i)
#pragma unroll
        for (int j = 0; j < 4; ++j) acc[i][j] = (f32x4){0.f, 0.f, 0.f, 0.f};

    int srow = tid >> 1;           // 0..127
    int sseg = (tid & 1) * 16;     // k offset 0 or 16
    int axrow = by * 128 + srow; if (axrow >= N) axrow = N - 1;
    const float* ax = x + (long)axrow * DF + sseg;
    const float* bxp = wT + (long)(bx * 128 + srow) * DF + sseg;
    unsigned short* Aw = &Al[srow * 32 + sseg];
    unsigned short* Bw = &Bl[srow * 32 + sseg];

    for (int kk = 0; kk < DF; kk += 32) {
        float4 a0 = *(const float4*)(ax + kk);
        float4 a1 = *(const float4*)(ax + kk + 4);
        float4 a2 = *(const float4*)(ax + kk + 8);
        float4 a3 = *(const float4*)(ax + kk + 12);
        float4 b0 = *(const float4*)(bxp + kk);
        float4 b1 = *(const float4*)(bxp + kk + 4);
        float4 b2 = *(const float4*)(bxp + kk + 8);
        float4 b3 = *(const float4*)(bxp + kk + 12);
        __syncthreads();   // previous iteration's frag reads complete
        uint4 pa, pb;
        pa.x = pack2(a0.x, a0.y); pa.y = pack2(a0.z, a0.w);
        pa.z = pack2(a1.x, a1.y); pa.w = pack2(a1.z, a1.w);
        *(uint4*)Aw = pa;
        pa.x = pack2(a2.x, a2.y); pa.y = pack2(a2.z, a2.w);
        pa.z = pack2(a3.x, a3.y); pa.w = pack2(a3.z, a3.w);
        *(uint4*)(Aw + 8) = pa;
        pb.x = pack2(b0.x, b0.y); pb.y = pack2(b0.z, b0.w);
        pb.z = pack2(b1.x, b1.y); pb.w = pack2(b1.z, b1.w);
        *(uint4*)Bw = pb;
        pb.x = pack2(b2.x, b2.y); pb.y = pack2(b2.z, b2.w);
        pb.z = pack2(b3.x, b3.y); pb.w = pack2(b3.z, b3.w);
        *(uint4*)(Bw + 8) = pb;
        __syncthreads();   // tiles ready

        short8 af[4], bf[4];
#pragma unroll
        for (int i = 0; i < 4; ++i)
            af[i] = *(const short8*)&Al[(wr * 64 + i * 16 + mi) * 32 + q * 8];
#pragma unroll
        for (int j = 0; j < 4; ++j)
            bf[j] = *(const short8*)&Bl[(wc * 64 + j * 16 + mi) * 32 + q * 8];
#pragma unroll
        for (int i = 0; i < 4; ++i)
#pragma unroll
            for (int j = 0; j < 4; ++j)
                acc[i][j] = __builtin_amdgcn_mfma_f32_16x16x32_bf16(af[i], bf[j], acc[i][j], 0, 0, 0);
    }

    // C/D layout: col = lane&15, row = (lane>>4)*4 + reg   [verified m89/m91]
#pragma unroll
    for (int i = 0; i < 4; ++i) {
        int base_row = by * 128 + wr * 64 + i * 16 + q * 4;
#pragma unroll
        for (int r = 0; r < 4; ++r) {
            int rg = base_row + r;
            if (rg < N) {
                float dv = dinv[rg];
#pragma unroll
                for (int j = 0; j < 4; ++j) {
                    int cg = bx * 128 + wc * 64 + j * 16 + mi;
                    h[(long)rg * DF + cg] = f2bf(dv * acc[i][j][r]);
                }
            }
        }
    }
}

// aggB: block per bucket. Counting-sort bucket edges into LDS, then one wave
// per row: split-wave gather identical to R4's agg inner loop.
__global__ __launch_bounds__(256) void aggb_kernel(const unsigned short* __restrict__ h,
                                                   const int2* __restrict__ bedge,
                                                   const int* __restrict__ bucket_base,
                                                   const float* __restrict__ dinv,
                                                   const float* __restrict__ bias,
                                                   float* __restrict__ out, int N) {
    __shared__ int2 ledge[CAP];
    __shared__ int cnt[RPB];
    __shared__ int lrs[RPB + 1];
    __shared__ int lfill[RPB];
    int b = blockIdx.x, t = threadIdx.x;
    int s = bucket_base[b], e = bucket_base[b + 1];
    int tot = e - s;
    int cap_end = s + (tot < CAP ? tot : CAP);
    if (t < RPB) { cnt[t] = 0; lfill[t] = 0; }
    __syncthreads();
    // phase 1: count by local row
    for (int i = s + t; i < cap_end; i += 256)
        atomicAdd(&cnt[bedge[i].x >> 17], 1);
    __syncthreads();
    // exclusive scan cnt -> lrs (lrs[RPB] = total)
    int myc = 0;
    if (t < RPB) { myc = cnt[t]; lrs[t] = myc; }
    __syncthreads();
    for (int off = 1; off < RPB; off <<= 1) {
        int v = (t < RPB && t >= off) ? lrs[t - off] : 0;
        __syncthreads();
        if (t < RPB) lrs[t] += v;
        __syncthreads();
    }
    if (t < RPB) {
        int iv = lrs[t];
        lrs[t] = iv - myc;
        if (t == RPB - 1) lrs[RPB] = iv;
    }
    __syncthreads();
    // phase 2: scatter into sorted LDS (L2-hot re-read)
    for (int i = s + t; i < cap_end; i += 256) {
        int2 ed = bedge[i];
        int rl = ed.x >> 17;
        int p = lrs[rl] + atomicAdd(&lfill[rl], 1);
        ledge[p] = make_int2(ed.x & 0x1FFFF, ed.y);
    }
    __syncthreads();
    // phase 3: wave per row
    int wv = t >> 6, lane = t & 63;
    int half = lane >> 5;
    int fl = (lane & 31) * 8;
    const unsigned short* hp = h + fl;
    for (int lr = wv; lr < RPB; lr += 4) {
        int r = b * RPB + lr;
        if (r >= N) break;
        int rs = lrs[lr], re = lrs[lr + 1];
        float a0 = 0, a1 = 0, a2 = 0, a3 = 0, a4 = 0, a5 = 0, a6 = 0, a7 = 0;
        int i = rs + half;
        for (; i + 6 < re; i += 8) {
            int2 e0 = ledge[i], e1 = ledge[i + 2], e2 = ledge[i + 4], e3 = ledge[i + 6];
            uint4 u0 = *(const uint4*)(hp + (long)e0.x * DF);
            uint4 u1 = *(const uint4*)(hp + (long)e1.x * DF);
            uint4 u2 = *(const uint4*)(hp + (long)e2.x * DF);
            uint4 u3 = *(const uint4*)(hp + (long)e3.x * DF);
            float v0 = __int_as_float(e0.y), v1 = __int_as_float(e1.y);
            float v2 = __int_as_float(e2.y), v3 = __int_as_float(e3.y);
            a0 += v0 * bflo(u0.x) + v1 * bflo(u1.x) + v2 * bflo(u2.x) + v3 * bflo(u3.x);
            a1 += v0 * bfhi(u0.x) + v1 * bfhi(u1.x) + v2 * bfhi(u2.x) + v3 * bfhi(u3.x);
            a2 += v0 * bflo(u0.y) + v1 * bflo(u1.y) + v2 * bflo(u2.y) + v3 * bflo(u3.y);
            a3 += v0 * bfhi(u0.y) + v1 * bfhi(u1.y) + v2 * bfhi(u2.y) + v3 * bfhi(u3.y);
            a4 += v0 * bflo(u0.z) + v1 * bflo(u1.z) + v2 * bflo(u2.z) + v3 * bflo(u3.z);
            a5 += v0 * bfhi(u0.z) + v1 * bfhi(u1.z) + v2 * bfhi(u2.z) + v3 * bfhi(u3.z);
            a6 += v0 * bflo(u0.w) + v1 * bflo(u1.w) + v2 * bflo(u2.w) + v3 * bflo(u3.w);
            a7 += v0 * bfhi(u0.w) + v1 * bfhi(u1.w) + v2 * bfhi(u2.w) + v3 * bfhi(u3.w);
        }
        for (; i < re; i += 2) {
            int2 e0 = ledge[i];
            float v0 = __int_as_float(e0.y);
            uint4 u0 = *(const uint4*)(hp + (long)e0.x * DF);
            a0 += v0 * bflo(u0.x); a1 += v0 * bfhi(u0.x);
            a2 += v0 * bflo(u0.y); a3 += v0 * bfhi(u0.y);
            a4 += v0 * bflo(u0.z); a5 += v0 * bfhi(u0.z);
            a6 += v0 * bflo(u0.w); a7 += v0 * bfhi(u0.w);
        }
        // overflow leftovers (normally empty): filter unsorted global tail
        for (int j = cap_end + half; j < e; j += 2) {
            int2 ed = bedge[j];
            if ((ed.x >> 17) == lr) {
                float v0 = __int_as_float(ed.y);
                uint4 u0 = *(const uint4*)(hp + (long)(ed.x & 0x1FFFF) * DF);
                a0 += v0 * bflo(u0.x); a1 += v0 * bfhi(u0.x);
                a2 += v0 * bflo(u0.y); a3 += v0 * bfhi(u0.y);
                a4 += v0 * bflo(u0.z); a5 += v0 * bfhi(u0.z);
                a6 += v0 * bflo(u0.w); a7 += v0 * bfhi(u0.w);
            }
        }
        a0 += __shfl_xor(a0, 32); a1 += __shfl_xor(a1, 32);
        a2 += __shfl_xor(a2, 32); a3 += __shfl_xor(a3, 32);
        a4 += __shfl_xor(a4, 32); a5 += __shfl_xor(a5, 32);
        a6 += __shfl_xor(a6, 32); a7 += __shfl_xor(a7, 32);
        if (half == 0) {
            float dr = dinv[r];
            float4 b0 = *(const float4*)(bias + fl);
            float4 b1 = *(const float4*)(bias + fl + 4);
            float4 o0, o1;
            o0.x = fmaxf(fmaf(dr, a0, b0.x), 0.f);
            o0.y = fmaxf(fmaf(dr, a1, b0.y), 0.f);
            o0.z = fmaxf(fmaf(dr, a2, b0.z), 0.f);
            o0.w = fmaxf(fmaf(dr, a3, b0.w), 0.f);
            o1.x = fmaxf(fmaf(dr, a4, b1.x), 0.f);
            o1.y = fmaxf(fmaf(dr, a5, b1.y), 0.f);
            o1.z = fmaxf(fmaf(dr, a6, b1.z), 0.f);
            o1.w = fmaxf(fmaf(dr, a7, b1.w), 0.f);
            *(float4*)(out + (long)r * DF + fl) = o0;
            *(float4*)(out + (long)r * DF + fl + 4) = o1;
        }
    }
}

extern "C" void kernel_launch(void* const* d_in, const int* in_sizes, int n_in,
                              void* d_out, int out_size, void* d_ws, size_t ws_size,
                              hipStream_t stream) {
    const float* x   = (const float*)d_in[0];
    const int* erow  = (const int*)d_in[1];
    const int* ecol  = (const int*)d_in[2];
    const float* ev  = (const float*)d_in[3];
    const float* w   = (const float*)d_in[4];
    const float* b   = (const float*)d_in[5];
    float* out = (float*)d_out;

    int N = in_sizes[0] / DF;
    int E = in_sizes[1];
    int NB = (N + RPB - 1) >> RSH;          // 782 (<=1024 supported)
    int NBLK = (E + CHUNK - 1) / CHUNK;     // 391 (<=512 supported)

    char* ws = (char*)d_ws;
    size_t Ea8 = (((size_t)E * 8) + 255) & ~(size_t)255;         // bedge
    size_t Hs  = (((size_t)N * DF * 2) + 255) & ~(size_t)255;    // h
    size_t Na  = (((size_t)N * 4) + 255) & ~(size_t)255;

    // Layout (~77.5 MB total; blockhist aliases h — dead before gemm):
    int2* bedge = (int2*)ws;
    char* reg2 = ws + Ea8;
    unsigned short* h = (unsigned short*)reg2;
    int* blockhist = (int*)reg2;            // alias of h (A1..A3 only)
    char* reg3 = reg2 + Hs;
    float* wT = (float*)reg3;
    float* dinv = (float*)(reg3 + 262144);
    int* buckettot = (int*)(reg3 + 262144 + Na);
    int* bucket_base = (int*)(reg3 + 262144 + Na + 8192);

    bhist_kernel<<<NBLK, 256, 0, stream>>>(erow, blockhist, NB, E);
    bscan_kernel<<<NB, 256, 0, stream>>>(blockhist, buckettot, NB, NBLK);
    btot_kernel<<<1, 1024, 0, stream>>>(buckettot, bucket_base, NB);
    bscatter_kernel<<<NBLK, 256, 0, stream>>>(erow, ecol, ev, blockhist, bucket_base, bedge, NB, E);
    deg_kernel<<<NB, 256, 0, stream>>>(bedge, bucket_base, dinv, N);
    transpose_kernel<<<dim3(8, 8), dim3(32, 8), 0, stream>>>(w, wT);
    gemm_kernel<<<dim3((N + 127) / 128, DF / 128), 256, 0, stream>>>(x, wT, dinv, h, N);
    aggb_kernel<<<NB, 256, 0, stream>>>(h, bedge, bucket_base, dinv, b, out, N);
}